// Round 2
// baseline (565.093 us; speedup 1.0000x reference)
//
#include <hip/hip_runtime.h>
#include <hip/hip_bf16.h>
#include <math.h>

// ---------------------------------------------------------------------------
// CrossModalAttention on MI355X (gfx950)
//   B=4, Cu=320, Cj=1024, H=W=64 (N=4096), ATTN_DIM=256, scale = 1/16
// Round 1: attention rewritten around 32x32x16 MFMA, swapped QK^T,
// in-register softmax (cvt_pk + permlane32_swap), j-split across wave pairs,
// conflict-free XOR-swizzled LDS tiles, async-stage (T14), defer-max (T13).
// ---------------------------------------------------------------------------

typedef unsigned short u16;
typedef __attribute__((ext_vector_type(8))) short bf16x8;
typedef __attribute__((ext_vector_type(4))) float f32x4;
typedef __attribute__((ext_vector_type(16))) float f32x16;
typedef __attribute__((ext_vector_type(4))) unsigned short u16x4;

#define NB 4
#define CU 320
#define CJ 1024
#define NN 4096
#define AD 256

// ws layout (bytes)
#define XU_OFF 0u
#define XJ_OFF 10485760u
#define QB_OFF 44040192u
#define KB_OFF 52428800u
#define VB_OFF 60817408u
#define WQ_OFF 71303168u
#define WK_OFF 71467008u
#define WV_OFF 71991296u
#define WO_OFF 72646656u
#define AO_OFF XU_OFF

__device__ __forceinline__ u16 f2b(float f) {
    union { float f; unsigned u; } v; v.f = f;
    unsigned u = v.u;
    unsigned r = (u + 0x7fffu + ((u >> 16) & 1u)) >> 16;
    return (u16)r;
}

__device__ __forceinline__ unsigned cvt_pk_bf16(float lo, float hi) {
    unsigned r;
    asm("v_cvt_pk_bf16_f32 %0, %1, %2" : "=v"(r) : "v"(lo), "v"(hi));
    return r;
}

// ---------------- weight cast ----------------
__global__ void wcast_kernel(const float* __restrict__ Wq, const float* __restrict__ Wk,
                             const float* __restrict__ Wv, const float* __restrict__ Wo,
                             u16* __restrict__ wq, u16* __restrict__ wk,
                             u16* __restrict__ wv, u16* __restrict__ wo) {
    int id = blockIdx.x * 256 + threadIdx.x;
    if (id < 81920) { wq[id] = f2b(Wq[id]); return; }
    id -= 81920;
    if (id < 262144) { wk[id] = f2b(Wk[id]); return; }
    id -= 262144;
    if (id < 327680) { wv[id] = f2b(Wv[id]); return; }
    id -= 327680;
    if (id < 102400) { wo[id] = f2b(Wo[id]); }
}

// ---------------- transpose [C][N] f32 -> [N][C] bf16 ----------------
__global__ __launch_bounds__(256) void transpose_cast_kernel(
        const float* __restrict__ in, u16* __restrict__ out, int C, int Nn) {
    __shared__ float tile[64][65];
    int b = blockIdx.z;
    int n0 = blockIdx.x * 64, c0 = blockIdx.y * 64;
    const float* src = in + (size_t)b * C * Nn;
    u16* dst = out + (size_t)b * Nn * C;
    int t = threadIdx.x;
    int nl = t & 63, cl = t >> 6;
    #pragma unroll
    for (int k = 0; k < 16; ++k) {
        int c = cl + k * 4;
        tile[c][nl] = src[(size_t)(c0 + c) * Nn + n0 + nl];
    }
    __syncthreads();
    int cl2 = t & 63, nl2 = t >> 6;
    #pragma unroll
    for (int k = 0; k < 16; ++k) {
        int n = nl2 + k * 4;
        dst[(size_t)(n0 + n) * C + c0 + cl2] = f2b(tile[cl2][n]);
    }
}

// ---------------- projection GEMM ----------------
template <int MODE>
__global__ __launch_bounds__(256) void proj_gemm_kernel(
        const u16* __restrict__ X, const u16* __restrict__ W,
        const float* __restrict__ bias, u16* __restrict__ out,
        int C, int O, float alpha) {
    int b = blockIdx.z;
    const u16* Xb = X + (size_t)b * NN * C;
    u16* outb = out + (size_t)b * NN * O;
    int lane = threadIdx.x & 63, wave = threadIdx.x >> 6;
    int r = lane & 15, h = lane >> 4;
    int i0 = blockIdx.x * 64 + wave * 16;
    int o0 = blockIdx.y * 64;

    f32x4 acc[4];
    #pragma unroll
    for (int nt = 0; nt < 4; ++nt) acc[nt] = (f32x4)0.0f;

    const u16* arow = Xb + (size_t)(i0 + r) * C + h * 8;
    for (int kk = 0; kk < C; kk += 32) {
        bf16x8 a = *(const bf16x8*)(arow + kk);
        #pragma unroll
        for (int nt = 0; nt < 4; ++nt) {
            bf16x8 bb = *(const bf16x8*)(W + (size_t)(o0 + nt * 16 + r) * C + kk + h * 8);
            acc[nt] = __builtin_amdgcn_mfma_f32_16x16x32_bf16(a, bb, acc[nt], 0, 0, 0);
        }
    }
    #pragma unroll
    for (int nt = 0; nt < 4; ++nt) {
        int o = o0 + nt * 16 + r;
        float bs = bias[o];
        if (MODE == 0) {
            #pragma unroll
            for (int rr = 0; rr < 4; ++rr) {
                int i = i0 + h * 4 + rr;
                outb[(size_t)i * O + o] = f2b((acc[nt][rr] + bs) * alpha);
            }
        } else {
            u16x4 v;
            #pragma unroll
            for (int rr = 0; rr < 4; ++rr) v[rr] = f2b((acc[nt][rr] + bs) * alpha);
            *(u16x4*)(outb + (size_t)o * NN + i0 + h * 4) = v;
        }
    }
}

// ---------------- flash attention (round-1 rewrite) ----------------
// Q: [B][N][256] bf16 (pre-scaled 1/16), K: [B][N][256], V: [B][320][N]
// 4 waves: (iw = wave>>1) picks 32-row q-slice, (jw = wave&1) picks j-half.
// S^T = mfma(K, Q): lane col = q-row, 16 regs = j rows. Softmax in-register.
// K tile LDS: [2][32 rows][32 slots16B], slot = c16 ^ row   (conflict-free)
// V tile LDS: [2][4 jslot][320 rows][16B], jslot = logical ^ (row&3)
__global__ __launch_bounds__(256, 1) void attn_kernel(
        const u16* __restrict__ Q, const u16* __restrict__ K,
        const u16* __restrict__ V, u16* __restrict__ AO) {
    __shared__ __align__(16) char smem[83968];
    u16* Kt = (u16*)smem;             // 2 * 16384 B
    u16* Vt = (u16*)(smem + 32768);   // 2 * 20480 B

    const int t = threadIdx.x;
    const int lane = t & 63, wave = t >> 6;
    const int iw = wave >> 1, jw = wave & 1;
    const int r = lane & 31, hi = lane >> 5;
    const int b = blockIdx.y;
    const int i0 = blockIdx.x * 64 + iw * 32;

    const u16* Qb = Q + ((size_t)b * NN + i0) * AD;
    const u16* Kb = K + (size_t)b * NN * AD;
    const u16* Vb = V + (size_t)b * CU * NN;

    // Q fragments: B-operand (col = q-row = r, k = kk*16 + hi*8 + e)
    bf16x8 q[16];
    #pragma unroll
    for (int kk = 0; kk < 16; ++kk)
        q[kk] = *(const bf16x8*)(Qb + (size_t)r * AD + kk * 16 + hi * 8);

    f32x16 o[10];
    #pragma unroll
    for (int ct = 0; ct < 10; ++ct) o[ct] = (f32x16)0.0f;
    float m = -INFINITY, lsum = 0.0f;

    bf16x8 kreg[8], vreg[10];

    // ---- stage helpers (T14 split: load early, write after barrier) ----
    #define LOAD_STAGE(JT)                                                        \
        {                                                                         \
            int jt_ = (JT);                                                       \
            _Pragma("unroll")                                                     \
            for (int n = 0; n < 8; ++n) {                                         \
                int tile = n >> 2;                                                \
                int chunk = (n & 3) * 256 + t;                                    \
                int row = chunk >> 5, c16 = chunk & 31;                           \
                int j = tile * 2048 + jt_ * 32 + row;                             \
                kreg[n] = *(const bf16x8*)(Kb + (size_t)j * AD + c16 * 8);        \
            }                                                                     \
            _Pragma("unroll")                                                     \
            for (int n = 0; n < 10; ++n) {                                        \
                int c = n * 256 + t;                                              \
                int tile = c / 1280;                                              \
                int rem = c % 1280;                                               \
                int js = rem / 320;                                               \
                int row = rem % 320;                                              \
                int j = tile * 2048 + jt_ * 32 + ((js ^ (row & 3)) << 3);         \
                vreg[n] = *(const bf16x8*)(Vb + (size_t)row * NN + j);            \
            }                                                                     \
        }

    #define WRITE_STAGE()                                                         \
        {                                                                         \
            _Pragma("unroll")                                                     \
            for (int n = 0; n < 8; ++n) {                                         \
                int tile = n >> 2;                                                \
                int chunk = (n & 3) * 256 + t;                                    \
                int row = chunk >> 5, c16 = chunk & 31;                           \
                *(bf16x8*)((char*)Kt + tile * 16384 + row * 512 +                 \
                           ((c16 ^ row) << 4)) = kreg[n];                         \
            }                                                                     \
            _Pragma("unroll")                                                     \
            for (int n = 0; n < 10; ++n) {                                        \
                int c = n * 256 + t;                                              \
                int tile = c / 1280;                                              \
                int rem = c % 1280;                                               \
                int js = rem / 320;                                               \
                int row = rem % 320;                                              \
                *(bf16x8*)((char*)Vt + tile * 20480 + js * 5120 + row * 16) =     \
                    vreg[n];                                                      \
            }                                                                     \
        }

    LOAD_STAGE(0);

    const char* Ktile = smem + jw * 16384;
    const char* Vtile = smem + 32768 + jw * 20480;

    for (int jt = 0; jt < 64; ++jt) {
        __syncthreads();           // prior tile reads done
        WRITE_STAGE();
        __syncthreads();
        if (jt < 63) LOAD_STAGE(jt + 1);

        // ---- QK^T (swapped): S^T[j][i] ----
        f32x16 s = (f32x16)0.0f;
        #pragma unroll
        for (int kk = 0; kk < 16; ++kk) {
            bf16x8 kf = *(const bf16x8*)(Ktile + r * 512 + (((2 * kk + hi) ^ r) << 4));
            s = __builtin_amdgcn_mfma_f32_32x32x16_bf16(kf, q[kk], s, 0, 0, 0);
        }

        // ---- in-register online softmax (defer-max, THR=8) ----
        float pmax = s[0];
        #pragma unroll
        for (int j = 1; j < 16; ++j) pmax = fmaxf(pmax, s[j]);
        pmax = fmaxf(pmax, __shfl_xor(pmax, 32));
        if (__any(pmax > m + 8.0f)) {
            float mn = fmaxf(m, pmax);
            float al = __expf(m - mn);
            m = mn;
            lsum *= al;
            #pragma unroll
            for (int ct = 0; ct < 10; ++ct) o[ct] *= al;
        }
        float p[16];
        float ps = 0.0f;
        #pragma unroll
        for (int j = 0; j < 16; ++j) { p[j] = __expf(s[j] - m); ps += p[j]; }
        ps += __shfl_xor(ps, 32);
        lsum += ps;

        // ---- P -> bf16 frags (cvt_pk + permlane32_swap), then PV ----
        #pragma unroll
        for (int ks = 0; ks < 2; ++ks) {
            unsigned a0 = cvt_pk_bf16(p[8 * ks + 0], p[8 * ks + 1]);
            unsigned a1 = cvt_pk_bf16(p[8 * ks + 2], p[8 * ks + 3]);
            unsigned b0 = cvt_pk_bf16(p[8 * ks + 4], p[8 * ks + 5]);
            unsigned b1 = cvt_pk_bf16(p[8 * ks + 6], p[8 * ks + 7]);
            asm("v_permlane32_swap_b32 %0, %1" : "+v"(a0), "+v"(b0));
            asm("v_permlane32_swap_b32 %0, %1" : "+v"(a1), "+v"(b1));
            union { unsigned w[4]; bf16x8 v; } u;
            u.w[0] = a0; u.w[1] = a1; u.w[2] = b0; u.w[3] = b1;
            bf16x8 pf = u.v;
            #pragma unroll
            for (int ct = 0; ct < 10; ++ct) {
                bf16x8 vf = *(const bf16x8*)(Vtile +
                    (((2 * ks + hi) ^ (r & 3)) * 5120) + (ct * 32 + r) * 16);
                o[ct] = __builtin_amdgcn_mfma_f32_32x32x16_bf16(vf, pf, o[ct], 0, 0, 0);
            }
        }
    }

    // ---- merge jw halves + store ----
    __syncthreads();
    float* mb = (float*)(smem + 82944);
    float* lb = (float*)(smem + 82944 + 512);
    if (lane < 32) {
        mb[(iw * 2 + jw) * 32 + r] = m;
        lb[(iw * 2 + jw) * 32 + r] = lsum;
    }
    __syncthreads();
    float mo = mb[(iw * 2 + (1 ^ jw)) * 32 + r];
    float lo = lb[(iw * 2 + (1 ^ jw)) * 32 + r];
    float M = fmaxf(m, mo);
    float f = __expf(m - M);
    float fo = __expf(mo - M);
    float inv = 1.0f / (lsum * f + lo * fo);

    float* fb = (float*)smem;   // [2 iw][32 i][324] f32 (aliases tiles)
    if (jw == 1) {
        #pragma unroll
        for (int ct = 0; ct < 10; ++ct)
            #pragma unroll
            for (int e = 0; e < 16; ++e) {
                int c = ct * 32 + (e & 3) + 8 * (e >> 2) + 4 * hi;
                fb[(iw * 32 + r) * 324 + c] = o[ct][e] * f;
            }
    }
    __syncthreads();
    unsigned w[80];
    if (jw == 0) {
        #pragma unroll
        for (int ct = 0; ct < 10; ++ct)
            #pragma unroll
            for (int g = 0; g < 4; ++g) {
                int cb = ct * 32 + 8 * g + 4 * hi;
                float v0 = (o[ct][4 * g + 0] * f + fb[(iw * 32 + r) * 324 + cb + 0]) * inv;
                float v1 = (o[ct][4 * g + 1] * f + fb[(iw * 32 + r) * 324 + cb + 1]) * inv;
                float v2 = (o[ct][4 * g + 2] * f + fb[(iw * 32 + r) * 324 + cb + 2]) * inv;
                float v3 = (o[ct][4 * g + 3] * f + fb[(iw * 32 + r) * 324 + cb + 3]) * inv;
                w[ct * 8 + g * 2 + 0] = cvt_pk_bf16(v0, v1);
                w[ct * 8 + g * 2 + 1] = cvt_pk_bf16(v2, v3);
            }
    }
    __syncthreads();
    u16* ob = (u16*)smem;       // [2 iw][32 i][328] bf16
    if (jw == 0) {
        #pragma unroll
        for (int ct = 0; ct < 10; ++ct)
            #pragma unroll
            for (int g = 0; g < 4; ++g) {
                int cb = ct * 32 + 8 * g + 4 * hi;
                *(unsigned*)(ob + (iw * 32 + r) * 328 + cb) = w[ct * 8 + g * 2 + 0];
                *(unsigned*)(ob + (iw * 32 + r) * 328 + cb + 2) = w[ct * 8 + g * 2 + 1];
            }
    }
    __syncthreads();
    u16* AOb = AO + ((size_t)b * NN + blockIdx.x * 64) * CU;
    #pragma unroll
    for (int n = 0; n < 10; ++n) {
        int id = n * 256 + t;
        int iw2 = id / 1280, rem = id % 1280;
        int row = rem / 40, c8 = rem % 40;
        bf16x8 val = *(const bf16x8*)(ob + (iw2 * 32 + row) * 328 + c8 * 8);
        *(bf16x8*)(AOb + (size_t)(iw2 * 32 + row) * CU + c8 * 8) = val;
    }
    #undef LOAD_STAGE
    #undef WRITE_STAGE
}

// ---------------- final projection + residual ----------------
__global__ __launch_bounds__(256) void final_gemm_kernel(
        const u16* __restrict__ AO, const u16* __restrict__ Wo,
        const float* __restrict__ bo, const float* __restrict__ unet,
        float* __restrict__ out) {
    int b = blockIdx.z;
    const u16* Ab = AO + (size_t)b * NN * CU;
    const float* ub = unet + (size_t)b * CU * NN;
    float* obp = out + (size_t)b * CU * NN;
    int lane = threadIdx.x & 63, wave = threadIdx.x >> 6;
    int r = lane & 15, h = lane >> 4;
    int i0 = blockIdx.x * 64 + wave * 16;
    int o0 = blockIdx.y * 64;

    f32x4 acc[4];
    #pragma unroll
    for (int nt = 0; nt < 4; ++nt) acc[nt] = (f32x4)0.0f;

    const u16* arow = Ab + (size_t)(i0 + r) * CU + h * 8;
    for (int kk = 0; kk < CU; kk += 32) {
        bf16x8 a = *(const bf16x8*)(arow + kk);
        #pragma unroll
        for (int nt = 0; nt < 4; ++nt) {
            bf16x8 wfr = *(const bf16x8*)(Wo + (size_t)(o0 + nt * 16 + r) * CU + kk + h * 8);
            acc[nt] = __builtin_amdgcn_mfma_f32_16x16x32_bf16(a, wfr, acc[nt], 0, 0, 0);
        }
    }
    #pragma unroll
    for (int nt = 0; nt < 4; ++nt) {
        int oc = o0 + nt * 16 + r;
        float bb = bo[oc];
        size_t base = (size_t)oc * NN + i0 + h * 4;
        f32x4 res;
        f32x4 u = *(const f32x4*)(ub + base);
        #pragma unroll
        for (int rr = 0; rr < 4; ++rr) res[rr] = acc[nt][rr] + bb + u[rr];
        *(f32x4*)(obp + base) = res;
    }
}

extern "C" void kernel_launch(void* const* d_in, const int* in_sizes, int n_in,
                              void* d_out, int out_size, void* d_ws, size_t ws_size,
                              hipStream_t stream) {
    const float* unet  = (const float*)d_in[0];
    const float* janus = (const float*)d_in[1];
    const float* Wq = (const float*)d_in[2];
    const float* bq = (const float*)d_in[3];
    const float* Wk = (const float*)d_in[4];
    const float* bk = (const float*)d_in[5];
    const float* Wv = (const float*)d_in[6];
    const float* bv = (const float*)d_in[7];
    const float* Wo = (const float*)d_in[8];
    const float* bo = (const float*)d_in[9];
    float* out = (float*)d_out;

    char* ws = (char*)d_ws;
    u16* Xu  = (u16*)(ws + XU_OFF);
    u16* Xj  = (u16*)(ws + XJ_OFF);
    u16* Qb  = (u16*)(ws + QB_OFF);
    u16* Kb  = (u16*)(ws + KB_OFF);
    u16* Vb  = (u16*)(ws + VB_OFF);
    u16* wq  = (u16*)(ws + WQ_OFF);
    u16* wk  = (u16*)(ws + WK_OFF);
    u16* wv  = (u16*)(ws + WV_OFF);
    u16* wo  = (u16*)(ws + WO_OFF);
    u16* AO  = (u16*)(ws + AO_OFF);

    wcast_kernel<<<3024, 256, 0, stream>>>(Wq, Wk, Wv, Wo, wq, wk, wv, wo);

    transpose_cast_kernel<<<dim3(64, 5, NB), 256, 0, stream>>>(unet, Xu, CU, NN);
    transpose_cast_kernel<<<dim3(64, 16, NB), 256, 0, stream>>>(janus, Xj, CJ, NN);

    proj_gemm_kernel<0><<<dim3(64, 4, NB), 256, 0, stream>>>(Xu, wq, bq, Qb, CU, AD, 0.0625f);
    proj_gemm_kernel<0><<<dim3(64, 4, NB), 256, 0, stream>>>(Xj, wk, bk, Kb, CJ, AD, 1.0f);
    proj_gemm_kernel<1><<<dim3(64, 5, NB), 256, 0, stream>>>(Xj, wv, bv, Vb, CJ, CU, 1.0f);

    attn_kernel<<<dim3(64, NB), 256, 0, stream>>>(Qb, Kb, Vb, AO);

    final_gemm_kernel<<<dim3(64, 5, NB), 256, 0, stream>>>(AO, wo, bo, unet, out);
}

// Round 3
// 421.083 us; speedup vs baseline: 1.3420x; 1.3420x over previous
//
#include <hip/hip_runtime.h>
#include <hip/hip_bf16.h>
#include <math.h>

// ---------------------------------------------------------------------------
// CrossModalAttention on MI355X (gfx950)
//   B=4, Cu=320, Cj=1024, H=W=64 (N=4096), ATTN_DIM=256, scale = 1/16
// Round 2: attn = 512-thread blocks, 8 waves (iw2 x cw2 x jw2), K/V staged via
// global_load_lds (pre-swizzled source, linear LDS), double-buffered 2-phase
// pipeline with counted vmcnt(9), raw s_barriers, exp2-domain softmax,
// s_setprio around MFMA clusters, XCD-bijective block swizzle.
// ---------------------------------------------------------------------------

typedef unsigned short u16;
typedef __attribute__((ext_vector_type(8))) short bf16x8;
typedef __attribute__((ext_vector_type(4))) float f32x4;
typedef __attribute__((ext_vector_type(16))) float f32x16;
typedef __attribute__((ext_vector_type(4))) unsigned short u16x4;

#define NB 4
#define CU 320
#define CJ 1024
#define NN 4096
#define AD 256

// ws layout (bytes)
#define XU_OFF 0u
#define XJ_OFF 10485760u
#define QB_OFF 44040192u
#define KB_OFF 52428800u
#define VB_OFF 60817408u
#define WQ_OFF 71303168u
#define WK_OFF 71467008u
#define WV_OFF 71991296u
#define WO_OFF 72646656u
#define AO_OFF XU_OFF

__device__ __forceinline__ u16 f2b(float f) {
    union { float f; unsigned u; } v; v.f = f;
    unsigned u = v.u;
    unsigned r = (u + 0x7fffu + ((u >> 16) & 1u)) >> 16;
    return (u16)r;
}

__device__ __forceinline__ unsigned cvt_pk_bf16(float lo, float hi) {
    unsigned r;
    asm("v_cvt_pk_bf16_f32 %0, %1, %2" : "=v"(r) : "v"(lo), "v"(hi));
    return r;
}

__device__ __forceinline__ float exp2_fast(float x) {
    float r;
    asm("v_exp_f32 %0, %1" : "=v"(r) : "v"(x));
    return r;
}

__device__ __forceinline__ void async_cp16(const u16* g, char* l) {
    __builtin_amdgcn_global_load_lds(
        (const __attribute__((address_space(1))) unsigned int*)g,
        (__attribute__((address_space(3))) unsigned int*)l, 16, 0, 0);
}

// ---------------- weight cast ----------------
__global__ void wcast_kernel(const float* __restrict__ Wq, const float* __restrict__ Wk,
                             const float* __restrict__ Wv, const float* __restrict__ Wo,
                             u16* __restrict__ wq, u16* __restrict__ wk,
                             u16* __restrict__ wv, u16* __restrict__ wo) {
    int id = blockIdx.x * 256 + threadIdx.x;
    if (id < 81920) { wq[id] = f2b(Wq[id]); return; }
    id -= 81920;
    if (id < 262144) { wk[id] = f2b(Wk[id]); return; }
    id -= 262144;
    if (id < 327680) { wv[id] = f2b(Wv[id]); return; }
    id -= 327680;
    if (id < 102400) { wo[id] = f2b(Wo[id]); }
}

// ---------------- transpose [C][N] f32 -> [N][C] bf16 ----------------
__global__ __launch_bounds__(256) void transpose_cast_kernel(
        const float* __restrict__ in, u16* __restrict__ out, int C, int Nn) {
    __shared__ float tile[64][65];
    int b = blockIdx.z;
    int n0 = blockIdx.x * 64, c0 = blockIdx.y * 64;
    const float* src = in + (size_t)b * C * Nn;
    u16* dst = out + (size_t)b * Nn * C;
    int t = threadIdx.x;
    int nl = t & 63, cl = t >> 6;
    #pragma unroll
    for (int k = 0; k < 16; ++k) {
        int c = cl + k * 4;
        tile[c][nl] = src[(size_t)(c0 + c) * Nn + n0 + nl];
    }
    __syncthreads();
    int cl2 = t & 63, nl2 = t >> 6;
    #pragma unroll
    for (int k = 0; k < 16; ++k) {
        int n = nl2 + k * 4;
        dst[(size_t)(n0 + n) * C + c0 + cl2] = f2b(tile[cl2][n]);
    }
}

// ---------------- projection GEMM ----------------
template <int MODE>
__global__ __launch_bounds__(256) void proj_gemm_kernel(
        const u16* __restrict__ X, const u16* __restrict__ W,
        const float* __restrict__ bias, u16* __restrict__ out,
        int C, int O, float alpha) {
    int b = blockIdx.z;
    const u16* Xb = X + (size_t)b * NN * C;
    u16* outb = out + (size_t)b * NN * O;
    int lane = threadIdx.x & 63, wave = threadIdx.x >> 6;
    int r = lane & 15, h = lane >> 4;
    int i0 = blockIdx.x * 64 + wave * 16;
    int o0 = blockIdx.y * 64;

    f32x4 acc[4];
    #pragma unroll
    for (int nt = 0; nt < 4; ++nt) acc[nt] = (f32x4)0.0f;

    const u16* arow = Xb + (size_t)(i0 + r) * C + h * 8;
    for (int kk = 0; kk < C; kk += 32) {
        bf16x8 a = *(const bf16x8*)(arow + kk);
        #pragma unroll
        for (int nt = 0; nt < 4; ++nt) {
            bf16x8 bb = *(const bf16x8*)(W + (size_t)(o0 + nt * 16 + r) * C + kk + h * 8);
            acc[nt] = __builtin_amdgcn_mfma_f32_16x16x32_bf16(a, bb, acc[nt], 0, 0, 0);
        }
    }
    #pragma unroll
    for (int nt = 0; nt < 4; ++nt) {
        int o = o0 + nt * 16 + r;
        float bs = bias[o];
        if (MODE == 0) {
            #pragma unroll
            for (int rr = 0; rr < 4; ++rr) {
                int i = i0 + h * 4 + rr;
                outb[(size_t)i * O + o] = f2b((acc[nt][rr] + bs) * alpha);
            }
        } else {
            u16x4 v;
            #pragma unroll
            for (int rr = 0; rr < 4; ++rr) v[rr] = f2b((acc[nt][rr] + bs) * alpha);
            *(u16x4*)(outb + (size_t)o * NN + i0 + h * 4) = v;
        }
    }
}

// ---------------- flash attention (round-2) ----------------
// Q: [B][N][256] bf16 (pre-scaled by log2e/16), K: [B][N][256], V: [B][320][N]
// 8 waves: iw = wave>>2 (32-row q-slice), cw = (wave>>1)&1 (160-ch half),
// jw = wave&1 (32-j slice of each 64-j tile).
// LDS per buffer (73728B): K [64 rows][32 slots 16B] slot=c16^row;
//                          V [2 jw][4 js][320 ch][16B] js=logical^(ch&3).
__global__ __launch_bounds__(512, 2) void attn_kernel(
        const u16* __restrict__ Q, const u16* __restrict__ K,
        const u16* __restrict__ V, u16* __restrict__ AO) {
    __shared__ __align__(16) char smem[148480];

    const int t = threadIdx.x;
    const int lane = t & 63;
    const int wave = t >> 6;
    const int iw = wave >> 2;
    const int cw = (wave >> 1) & 1;
    const int jw = wave & 1;
    const int r = lane & 31, hi = lane >> 5;

    int linear = blockIdx.y * 64 + blockIdx.x;
    int swz = (linear & 7) * 32 + (linear >> 3);
    int b = swz >> 6;
    int i0 = (swz & 63) * 64;

    const u16* Qb = Q + ((size_t)b * NN + i0 + iw * 32) * AD;
    const u16* Kb = K + (size_t)b * NN * AD;
    const u16* Vb = V + (size_t)b * CU * NN;

    // per-thread staging source offsets (elements), LDS dest is linear
    int goff[9];
    unsigned wb = (unsigned)__builtin_amdgcn_readfirstlane((t & ~63) * 16);
    #pragma unroll
    for (int n = 0; n < 4; ++n) {
        int c = n * 512 + t;
        int row = c >> 5, c16 = c & 31;
        goff[n] = row * 256 + ((c16 ^ (row & 31)) << 3);
    }
    #pragma unroll
    for (int n = 4; n < 9; ++n) {
        int cc = (n - 4) * 512 + t;
        int jj = cc / 1280, rem = cc % 1280;
        int js = rem / 320, row = rem % 320;
        goff[n] = row * NN + jj * 32 + ((js ^ (row & 3)) << 3);
    }

    #define STAGE(bufsel, kptr, vptr) do {                                        \
        unsigned bo_ = (unsigned)(bufsel) * 73728u;                               \
        _Pragma("unroll")                                                         \
        for (int n_ = 0; n_ < 4; ++n_)                                            \
            async_cp16((kptr) + goff[n_], smem + bo_ + n_ * 8192 + wb);           \
        _Pragma("unroll")                                                         \
        for (int n_ = 4; n_ < 9; ++n_)                                            \
            async_cp16((vptr) + goff[n_], smem + bo_ + 32768 + (n_ - 4) * 8192 + wb); \
    } while (0)

    // Q fragments (B-operand: col = q-row = r, k = kk*16 + hi*8 + e)
    bf16x8 q[16];
    #pragma unroll
    for (int kk = 0; kk < 16; ++kk)
        q[kk] = *(const bf16x8*)(Qb + (size_t)r * AD + kk * 16 + hi * 8);

    f32x16 o[5];
    #pragma unroll
    for (int ct = 0; ct < 5; ++ct) o[ct] = (f32x16)0.0f;
    float m = -INFINITY, lsum = 0.0f;

    STAGE(0, Kb, Vb);
    const u16* kp = Kb + 16384;
    const u16* vp = Vb + 64;
    int cur = 0;

    for (int jt = 0; jt < 64; ++jt) {
        if (jt < 63) {
            STAGE(cur ^ 1, kp, vp);
            kp += 16384; vp += 64;
            asm volatile("s_waitcnt vmcnt(9)" ::: "memory");
        } else {
            asm volatile("s_waitcnt vmcnt(0)" ::: "memory");
        }
        __builtin_amdgcn_s_barrier();
        asm volatile("" ::: "memory");

        const char* Kt = smem + cur * 73728 + jw * 16384;
        const char* Vt = smem + cur * 73728 + 32768 + jw * 20480;

        // ---- QK^T (swapped): s = S^T, lane col = q-row r, regs = 16 j + hi*... ----
        f32x16 sa = (f32x16)0.0f, sb = (f32x16)0.0f;
        __builtin_amdgcn_s_setprio(1);
        #pragma unroll
        for (int kk = 0; kk < 8; ++kk) {
            bf16x8 k0 = *(const bf16x8*)(Kt + r * 512 + (((2 * kk + hi) ^ r) << 4));
            bf16x8 k1 = *(const bf16x8*)(Kt + r * 512 + (((2 * (kk + 8) + hi) ^ r) << 4));
            sa = __builtin_amdgcn_mfma_f32_32x32x16_bf16(k0, q[kk], sa, 0, 0, 0);
            sb = __builtin_amdgcn_mfma_f32_32x32x16_bf16(k1, q[kk + 8], sb, 0, 0, 0);
        }
        __builtin_amdgcn_s_setprio(0);
        f32x16 s = sa + sb;

        // ---- in-register online softmax (exp2 domain, defer-max THR=8) ----
        float pmax = s[0];
        #pragma unroll
        for (int e = 1; e < 16; ++e) pmax = fmaxf(pmax, s[e]);
        pmax = fmaxf(pmax, __shfl_xor(pmax, 32));
        if (__any(pmax > m + 8.0f)) {
            float mn = fmaxf(m, pmax);
            float al = exp2_fast(m - mn);
            m = mn;
            lsum *= al;
            #pragma unroll
            for (int ct = 0; ct < 5; ++ct) o[ct] *= al;
        }
        float p[16];
        float ps = 0.0f;
        #pragma unroll
        for (int e = 0; e < 16; ++e) { p[e] = exp2_fast(s[e] - m); ps += p[e]; }
        ps += __shfl_xor(ps, 32);
        lsum += ps;

        // ---- P -> bf16 frags (cvt_pk + permlane32_swap), then PV ----
        __builtin_amdgcn_s_setprio(1);
        #pragma unroll
        for (int ks = 0; ks < 2; ++ks) {
            unsigned a0 = cvt_pk_bf16(p[8 * ks + 0], p[8 * ks + 1]);
            unsigned a1 = cvt_pk_bf16(p[8 * ks + 2], p[8 * ks + 3]);
            unsigned b0 = cvt_pk_bf16(p[8 * ks + 4], p[8 * ks + 5]);
            unsigned b1 = cvt_pk_bf16(p[8 * ks + 6], p[8 * ks + 7]);
            asm("v_permlane32_swap_b32 %0, %1" : "+v"(a0), "+v"(b0));
            asm("v_permlane32_swap_b32 %0, %1" : "+v"(a1), "+v"(b1));
            union { unsigned w[4]; bf16x8 v; } u;
            u.w[0] = a0; u.w[1] = a1; u.w[2] = b0; u.w[3] = b1;
            #pragma unroll
            for (int ct = 0; ct < 5; ++ct) {
                bf16x8 vf = *(const bf16x8*)(Vt + (((2 * ks + hi) ^ (r & 3)) * 5120)
                                             + (cw * 160 + ct * 32 + r) * 16);
                o[ct] = __builtin_amdgcn_mfma_f32_32x32x16_bf16(vf, u.v, o[ct], 0, 0, 0);
            }
        }
        __builtin_amdgcn_s_setprio(0);
        asm volatile("" ::: "memory");
        __builtin_amdgcn_s_barrier();   // all waves done reading buf[cur]
        asm volatile("" ::: "memory");
        cur ^= 1;
    }

    // ---- merge jw halves ----
    float* mlb = (float*)(smem + 147456);
    if (cw == 0 && lane < 32) {
        mlb[(iw * 2 + jw) * 32 + r] = m;
        mlb[128 + (iw * 2 + jw) * 32 + r] = lsum;
    }
    __builtin_amdgcn_s_barrier();
    asm volatile("" ::: "memory");
    float mo = mlb[(iw * 2 + (jw ^ 1)) * 32 + r];
    float lo = mlb[128 + (iw * 2 + (jw ^ 1)) * 32 + r];
    float M = fmaxf(m, mo);
    float f = exp2_fast(m - M);
    float fo = exp2_fast(mo - M);
    float inv = 1.0f / (lsum * f + lo * fo);

    float* fb = (float*)smem;          // [2 iw][32 i][321] f32
    if (jw == 1) {
        #pragma unroll
        for (int ct = 0; ct < 5; ++ct)
            #pragma unroll
            for (int e = 0; e < 16; ++e) {
                int c = cw * 160 + ct * 32 + (e & 3) + 8 * (e >> 2) + 4 * hi;
                fb[(iw * 32 + r) * 321 + c] = o[ct][e] * f;
            }
    }
    asm volatile("" ::: "memory");
    __builtin_amdgcn_s_barrier();
    asm volatile("" ::: "memory");
    u16* ob = (u16*)(smem + 82176);    // [2 iw][32 i][328] u16
    if (jw == 0) {
        #pragma unroll
        for (int ct = 0; ct < 5; ++ct)
            #pragma unroll
            for (int g = 0; g < 4; ++g) {
                int cb = cw * 160 + ct * 32 + 8 * g + 4 * hi;
                const float* fr = &fb[(iw * 32 + r) * 321 + cb];
                float v0 = (o[ct][4 * g + 0] * f + fr[0]) * inv;
                float v1 = (o[ct][4 * g + 1] * f + fr[1]) * inv;
                float v2 = (o[ct][4 * g + 2] * f + fr[2]) * inv;
                float v3 = (o[ct][4 * g + 3] * f + fr[3]) * inv;
                *(unsigned*)(ob + (iw * 32 + r) * 328 + cb) = cvt_pk_bf16(v0, v1);
                *(unsigned*)(ob + (iw * 32 + r) * 328 + cb + 2) = cvt_pk_bf16(v2, v3);
            }
    }
    asm volatile("" ::: "memory");
    __builtin_amdgcn_s_barrier();
    asm volatile("" ::: "memory");

    u16* AOb = AO + ((size_t)b * NN + i0) * CU;
    #pragma unroll
    for (int n = 0; n < 5; ++n) {
        int id = n * 512 + t;
        int row = id / 40, c8 = id % 40;
        bf16x8 val = *(const bf16x8*)(ob + row * 328 + c8 * 8);
        *(bf16x8*)(AOb + (size_t)row * CU + c8 * 8) = val;
    }
    #undef STAGE
}

// ---------------- final projection + residual ----------------
__global__ __launch_bounds__(256) void final_gemm_kernel(
        const u16* __restrict__ AO, const u16* __restrict__ Wo,
        const float* __restrict__ bo, const float* __restrict__ unet,
        float* __restrict__ out) {
    int b = blockIdx.z;
    const u16* Ab = AO + (size_t)b * NN * CU;
    const float* ub = unet + (size_t)b * CU * NN;
    float* obp = out + (size_t)b * CU * NN;
    int lane = threadIdx.x & 63, wave = threadIdx.x >> 6;
    int r = lane & 15, h = lane >> 4;
    int i0 = blockIdx.x * 64 + wave * 16;
    int o0 = blockIdx.y * 64;

    f32x4 acc[4];
    #pragma unroll
    for (int nt = 0; nt < 4; ++nt) acc[nt] = (f32x4)0.0f;

    const u16* arow = Ab + (size_t)(i0 + r) * CU + h * 8;
    for (int kk = 0; kk < CU; kk += 32) {
        bf16x8 a = *(const bf16x8*)(arow + kk);
        #pragma unroll
        for (int nt = 0; nt < 4; ++nt) {
            bf16x8 wfr = *(const bf16x8*)(Wo + (size_t)(o0 + nt * 16 + r) * CU + kk + h * 8);
            acc[nt] = __builtin_amdgcn_mfma_f32_16x16x32_bf16(a, wfr, acc[nt], 0, 0, 0);
        }
    }
    #pragma unroll
    for (int nt = 0; nt < 4; ++nt) {
        int oc = o0 + nt * 16 + r;
        float bb = bo[oc];
        size_t base = (size_t)oc * NN + i0 + h * 4;
        f32x4 res;
        f32x4 u = *(const f32x4*)(ub + base);
        #pragma unroll
        for (int rr = 0; rr < 4; ++rr) res[rr] = acc[nt][rr] + bb + u[rr];
        *(f32x4*)(obp + base) = res;
    }
}

extern "C" void kernel_launch(void* const* d_in, const int* in_sizes, int n_in,
                              void* d_out, int out_size, void* d_ws, size_t ws_size,
                              hipStream_t stream) {
    const float* unet  = (const float*)d_in[0];
    const float* janus = (const float*)d_in[1];
    const float* Wq = (const float*)d_in[2];
    const float* bq = (const float*)d_in[3];
    const float* Wk = (const float*)d_in[4];
    const float* bk = (const float*)d_in[5];
    const float* Wv = (const float*)d_in[6];
    const float* bv = (const float*)d_in[7];
    const float* Wo = (const float*)d_in[8];
    const float* bo = (const float*)d_in[9];
    float* out = (float*)d_out;

    char* ws = (char*)d_ws;
    u16* Xu  = (u16*)(ws + XU_OFF);
    u16* Xj  = (u16*)(ws + XJ_OFF);
    u16* Qb  = (u16*)(ws + QB_OFF);
    u16* Kb  = (u16*)(ws + KB_OFF);
    u16* Vb  = (u16*)(ws + VB_OFF);
    u16* wq  = (u16*)(ws + WQ_OFF);
    u16* wk  = (u16*)(ws + WK_OFF);
    u16* wv  = (u16*)(ws + WV_OFF);
    u16* wo  = (u16*)(ws + WO_OFF);
    u16* AO  = (u16*)(ws + AO_OFF);

    wcast_kernel<<<3024, 256, 0, stream>>>(Wq, Wk, Wv, Wo, wq, wk, wv, wo);

    transpose_cast_kernel<<<dim3(64, 5, NB), 256, 0, stream>>>(unet, Xu, CU, NN);
    transpose_cast_kernel<<<dim3(64, 16, NB), 256, 0, stream>>>(janus, Xj, CJ, NN);

    // Q pre-scaled by (1/16) * log2(e) so softmax runs in exp2 domain
    proj_gemm_kernel<0><<<dim3(64, 4, NB), 256, 0, stream>>>(Xu, wq, bq, Qb, CU, AD, 0.0901684411f);
    proj_gemm_kernel<0><<<dim3(64, 4, NB), 256, 0, stream>>>(Xj, wk, bk, Kb, CJ, AD, 1.0f);
    proj_gemm_kernel<1><<<dim3(64, 5, NB), 256, 0, stream>>>(Xj, wv, bv, Vb, CJ, CU, 1.0f);

    attn_kernel<<<dim3(64, NB), 512, 0, stream>>>(Qb, Kb, Vb, AO);

    final_gemm_kernel<<<dim3(64, 5, NB), 256, 0, stream>>>(AO, wo, bo, unet, out);
}